// Round 4
// baseline (421.760 us; speedup 1.0000x reference)
//
#include <hip/hip_runtime.h>
#include <cmath>

typedef __attribute__((ext_vector_type(8))) short bf16x8;
typedef __attribute__((ext_vector_type(4))) short bf16x4;
typedef __attribute__((ext_vector_type(4))) float f32x4;

__device__ __forceinline__ float bf2f(ushort u) {
    union { unsigned int u; float f; } c;
    c.u = ((unsigned int)u) << 16;
    return c.f;
}
__device__ __forceinline__ ushort f2bf(float f) {
    union { float f; unsigned int u; } c;
    c.f = f;
    unsigned int lsb = (c.u >> 16) & 1u;
    return (ushort)((c.u + 0x7fffu + lsb) >> 16);
}

// 8-bf16 LDS load from an 8B-aligned address
__device__ __forceinline__ bf16x8 lds_ld8(const ushort* p) {
    const bf16x4 lo = *(const bf16x4*)p;
    const bf16x4 hi = *(const bf16x4*)(p + 4);
    bf16x8 r;
    r[0] = lo[0]; r[1] = lo[1]; r[2] = lo[2]; r[3] = lo[3];
    r[4] = hi[0]; r[5] = hi[1]; r[6] = hi[2]; r[7] = hi[3];
    return r;
}

// async global->LDS, 16B per lane. LDS dest = wave-uniform base + lane*16.
__device__ __forceinline__ void gl2lds16(const ushort* g, ushort* l) {
    __builtin_amdgcn_global_load_lds((const __attribute__((address_space(1))) void*)g,
                                     (__attribute__((address_space(3))) void*)l,
                                     16, 0, 0);
}

// ---------------------------------------------------------------------------
__global__ __launch_bounds__(256) void cast_bf16(const float* __restrict__ in,
                                                 ushort* __restrict__ out, int n)
{
    int i = (blockIdx.x * 256 + threadIdx.x) * 4;
    if (i < n) {
        const float4 v = *(const float4*)(in + i);
        ushort4 o;
        o.x = f2bf(v.x); o.y = f2bf(v.y); o.z = f2bf(v.z); o.w = f2bf(v.w);
        *(ushort4*)(out + i) = o;
    }
}

// transpose + cast: in (R,C) fp32 row-major -> out (C,R) bf16 row-major
__global__ __launch_bounds__(256) void transpose_cast(const float* __restrict__ in,
                                                      ushort* __restrict__ out,
                                                      int R, int C)
{
    __shared__ float t[32][33];
    const int tx = threadIdx.x & 31;
    const int ty = threadIdx.x >> 5;
    const int r0 = blockIdx.y << 5;
    const int c0 = blockIdx.x << 5;
    #pragma unroll
    for (int i = ty; i < 32; i += 8)
        t[i][tx] = in[(size_t)(r0 + i) * C + c0 + tx];
    __syncthreads();
    #pragma unroll
    for (int i = ty; i < 32; i += 8)
        out[(size_t)(c0 + i) * R + r0 + tx] = f2bf(t[tx][i]);
}

// b_cat[n] = sum_o bq[o]*wuk[n][o] for n<512, else 0   (fp32, n in 0..1023)
__global__ __launch_bounds__(256) void bias_fold(const float* __restrict__ bq,
                                                 const float* __restrict__ wuk,
                                                 float* __restrict__ b_cat)
{
    const int n = blockIdx.x * 256 + threadIdx.x;
    float s = 0.f;
    if (n < 512) {
        for (int o = 0; o < 1024; o += 4) {
            const float4 w = *(const float4*)(wuk + (size_t)n * 1024 + o);
            const float4 q = *(const float4*)(bq + o);
            s = fmaf(q.x, w.x, s); s = fmaf(q.y, w.y, s);
            s = fmaf(q.z, w.z, s); s = fmaf(q.w, w.w, s);
        }
    }
    b_cat[n] = s;
}

// ---------------------------------------------------------------------------
// bf16 MFMA GEMM: C[M,N] = A[M,K] @ Bt[N,K]^T (+bias), strided rows.
// 128x128x32 tile, 256 threads = 4 waves (2x2), each wave 4x4 of 16x16x32.
// ---------------------------------------------------------------------------
template<bool OUT_F32, bool HAS_BIAS>
__global__ __launch_bounds__(256) void gemm_bt(const ushort* __restrict__ A,
                                               const ushort* __restrict__ Bt,
                                               const float* __restrict__ bias,
                                               void* __restrict__ Cv,
                                               int M, int N, int K,
                                               int lda, int ldb, int ldc)
{
    __shared__ ushort As[128 * 32];
    __shared__ ushort Bs[128 * 32];

    const int tid  = threadIdx.x;
    const int wave = tid >> 6;
    const int lane = tid & 63;
    const int row0 = blockIdx.y << 7;
    const int col0 = blockIdx.x << 7;

    const int srow = lane >> 2;
    const int skc  = (lane & 3) << 3;
    const ushort* Ag0 = A  + (size_t)(row0 + wave * 32 +      srow) * lda + skc;
    const ushort* Ag1 = A  + (size_t)(row0 + wave * 32 + 16 + srow) * lda + skc;
    const ushort* Bg0 = Bt + (size_t)(col0 + wave * 32 +      srow) * ldb + skc;
    const ushort* Bg1 = Bt + (size_t)(col0 + wave * 32 + 16 + srow) * ldb + skc;
    ushort* Asl0 = &As[(wave * 2 + 0) * 512];
    ushort* Asl1 = &As[(wave * 2 + 1) * 512];
    ushort* Bsl0 = &Bs[(wave * 2 + 0) * 512];
    ushort* Bsl1 = &Bs[(wave * 2 + 1) * 512];

    const int wr = (wave >> 1) << 6;
    const int wc = (wave & 1) << 6;
    const int ln = lane & 15;
    const int hi = lane >> 4;
    const int a_off = (wr + ln) * 32 + hi * 8;
    const int b_off = (wc + ln) * 32 + hi * 8;

    f32x4 acc[4][4];
    #pragma unroll
    for (int i = 0; i < 4; ++i)
        #pragma unroll
        for (int j = 0; j < 4; ++j)
            acc[i][j] = (f32x4){0.f, 0.f, 0.f, 0.f};

    for (int k0 = 0; k0 < K; k0 += 32) {
        __syncthreads();
        gl2lds16(Ag0 + k0, Asl0);
        gl2lds16(Ag1 + k0, Asl1);
        gl2lds16(Bg0 + k0, Bsl0);
        gl2lds16(Bg1 + k0, Bsl1);
        __syncthreads();

        bf16x8 a[4], b[4];
        #pragma unroll
        for (int i = 0; i < 4; ++i) a[i] = *(const bf16x8*)&As[a_off + i * 512];
        #pragma unroll
        for (int j = 0; j < 4; ++j) b[j] = *(const bf16x8*)&Bs[b_off + j * 512];
        #pragma unroll
        for (int i = 0; i < 4; ++i)
            #pragma unroll
            for (int j = 0; j < 4; ++j)
                acc[i][j] = __builtin_amdgcn_mfma_f32_16x16x32_bf16(a[i], b[j], acc[i][j], 0, 0, 0);
    }

    #pragma unroll
    for (int j = 0; j < 4; ++j) {
        const int col = col0 + wc + (j << 4) + ln;
        const float bb = HAS_BIAS ? bias[col] : 0.f;
        #pragma unroll
        for (int i = 0; i < 4; ++i) {
            const int rbase = row0 + wr + (i << 4) + (hi << 2);
            #pragma unroll
            for (int r = 0; r < 4; ++r) {
                const float v = acc[i][j][r] + bb;
                if (OUT_F32) ((float*)Cv)[(size_t)(rbase + r) * ldc + col] = v;
                else         ((ushort*)Cv)[(size_t)(rbase + r) * ldc + col] = f2bf(v);
            }
        }
    }
}

// ---------------------------------------------------------------------------
// MFMA flash attention, barrier-free. Block = (b, h, 64q); 4 waves x 16q.
//   qc: fused (8192, 1024) bf16 — cols [0,512) = q_latent, [512,1024) = K
//   vT: (1024, 8192) bf16 — row (h*64+c), col (b*1024+s)
// QK^T: 1 MFMA per 16x16 (d=32), K-frags direct global.
// PV: P via wave-local LDS roundtrip (C->A layout), V-frags direct global.
// Mask arithmetic exact fp32 (__fadd_rn/__fmul_rn) as in rounds 2-3.
// ---------------------------------------------------------------------------
__global__ __launch_bounds__(256) void attn_mfma(const ushort* __restrict__ qc,
                                                 const ushort* __restrict__ vT,
                                                 const float* __restrict__ mask,
                                                 ushort* __restrict__ z)
{
    __shared__ ushort Ps[4][16][68];     // per-wave P: [wave][q][key]

    const int tid  = threadIdx.x;
    const int wave = tid >> 6;
    const int lane = tid & 63;
    const int ln   = lane & 15;
    const int hi   = lane >> 4;
    const int qt = blockIdx.x, h = blockIdx.y, b = blockIdx.z;
    const int s0q = qt << 6;

    const ushort* ql = qc;
    const ushort* kl = qc + 512;

    // Q A-frag: query = s0q+16*wave+ln, dims hi*8..+7 (one frag covers d=32)
    const bf16x8 aq = *(const bf16x8*)(ql + (size_t)(b * 1024 + s0q + wave * 16 + ln) * 1024 + h * 32 + hi * 8);

    float mqv[4];
    #pragma unroll
    for (int r = 0; r < 4; ++r)
        mqv[r] = mask[b * 1024 + s0q + wave * 16 + hi * 4 + r];

    f32x4 acc_o[4];
    #pragma unroll
    for (int jo = 0; jo < 4; ++jo) acc_o[jo] = (f32x4){0.f, 0.f, 0.f, 0.f};
    float m_run[4] = {-INFINITY, -INFINITY, -INFINITY, -INFINITY};
    float l_run[4] = {0.f, 0.f, 0.f, 0.f};

    const float scale = 0.17677669529663687f;   // 1/sqrt(32)

    for (int kt = 0; kt < 16; ++kt) {
        const int s0k = kt << 6;

        // K B-frags (direct global) + QK MFMAs
        bf16x8 bk[4];
        #pragma unroll
        for (int j = 0; j < 4; ++j)
            bk[j] = *(const bf16x8*)(kl + (size_t)(b * 1024 + s0k + j * 16 + ln) * 1024 + h * 32 + hi * 8);
        f32x4 accS[4];
        #pragma unroll
        for (int j = 0; j < 4; ++j)
            accS[j] = __builtin_amdgcn_mfma_f32_16x16x32_bf16(aq, bk[j], (f32x4){0.f, 0.f, 0.f, 0.f}, 0, 0, 0);

        float mkv[4];
        #pragma unroll
        for (int j = 0; j < 4; ++j) mkv[j] = mask[b * 1024 + s0k + j * 16 + ln];

        // online softmax per C-layout row (row = hi*4+r, col = j*16+ln)
        float pj[4][4];
        #pragma unroll
        for (int r = 0; r < 4; ++r) {
            float v[4];
            float mx = -INFINITY;
            #pragma unroll
            for (int j = 0; j < 4; ++j) {
                const float m2 = fminf(1.f, __fadd_rn(mqv[r], mkv[j]));
                const float t  = __fmul_rn(m2, -1.0e9f);
                v[j] = __fadd_rn(__fmul_rn(accS[j][r], scale), t);
                mx = fmaxf(mx, v[j]);
            }
            #pragma unroll
            for (int off = 8; off >= 1; off >>= 1)
                mx = fmaxf(mx, __shfl_xor(mx, off));
            const float m_new = fmaxf(m_run[r], mx);
            const float alpha = __expf(m_run[r] - m_new);
            float sum = 0.f;
            #pragma unroll
            for (int j = 0; j < 4; ++j) {
                const float e = __expf(v[j] - m_new);
                pj[r][j] = e;
                sum += e;
            }
            #pragma unroll
            for (int off = 8; off >= 1; off >>= 1)
                sum += __shfl_xor(sum, off);
            l_run[r] = l_run[r] * alpha + sum;
            m_run[r] = m_new;
            #pragma unroll
            for (int jo = 0; jo < 4; ++jo) acc_o[jo][r] *= alpha;
        }

        // P: C-layout -> per-wave LDS -> A-frags (wave-local, no barrier)
        #pragma unroll
        for (int r = 0; r < 4; ++r)
            #pragma unroll
            for (int j = 0; j < 4; ++j)
                Ps[wave][hi * 4 + r][j * 16 + ln] = f2bf(pj[r][j]);

        const bf16x8 pa0 = lds_ld8(&Ps[wave][ln][hi * 8]);
        const bf16x8 pa1 = lds_ld8(&Ps[wave][ln][32 + hi * 8]);

        // V B-frags direct from vT rows + PV MFMAs
        #pragma unroll
        for (int jo = 0; jo < 4; ++jo) {
            const ushort* vrow = vT + (size_t)(h * 64 + jo * 16 + ln) * 8192 + b * 1024 + s0k;
            const bf16x8 bv0 = *(const bf16x8*)(vrow + hi * 8);
            const bf16x8 bv1 = *(const bf16x8*)(vrow + 32 + hi * 8);
            acc_o[jo] = __builtin_amdgcn_mfma_f32_16x16x32_bf16(pa0, bv0, acc_o[jo], 0, 0, 0);
            acc_o[jo] = __builtin_amdgcn_mfma_f32_16x16x32_bf16(pa1, bv1, acc_o[jo], 0, 0, 0);
        }
    }

    float invl[4];
    #pragma unroll
    for (int r = 0; r < 4; ++r) invl[r] = 1.f / l_run[r];
    #pragma unroll
    for (int jo = 0; jo < 4; ++jo)
        #pragma unroll
        for (int r = 0; r < 4; ++r)
            z[(size_t)(b * 1024 + s0q + wave * 16 + hi * 4 + r) * 1024 + h * 64 + jo * 16 + ln]
                = f2bf(acc_o[jo][r] * invl[r]);
}

// ---------------------------------------------------------------------------
extern "C" void kernel_launch(void* const* d_in, const int* in_sizes, int n_in,
                              void* d_out, int out_size, void* d_ws, size_t ws_size,
                              hipStream_t stream)
{
    const float* x     = (const float*)d_in[0];
    const float* mask  = (const float*)d_in[1];
    const float* wq    = (const float*)d_in[2];
    const float* bq    = (const float*)d_in[3];
    const float* w_ckv = (const float*)d_in[4];
    const float* wuk   = (const float*)d_in[5];
    const float* wuv   = (const float*)d_in[6];
    const float* wo    = (const float*)d_in[7];
    const float* bo    = (const float*)d_in[8];
    float* out = (float*)d_out;

    char* ws = (char*)d_ws;
    ushort* x_bf   = (ushort*)(ws);                         // 16 MB
    ushort* qc     = (ushort*)(ws + (size_t)(16u << 20));   // 16 MB (q_latent|K)
    ushort* vT     = (ushort*)(ws + (size_t)(32u << 20));   // 16 MB (1024,8192)
    ushort* z      = (ushort*)(ws + (size_t)(48u << 20));   // 16 MB
    ushort* wq_bf  = (ushort*)(ws + (size_t)(64u << 20));   //  2 MB
    ushort* wuk_bf = (ushort*)(ws + (size_t)(66u << 20));   //  1 MB
    ushort* wuv_t  = (ushort*)(ws + (size_t)(67u << 20));   //  1 MB
    ushort* wo_t   = (ushort*)(ws + (size_t)(68u << 20));   //  2 MB
    ushort* wcat_t = (ushort*)(ws + (size_t)(70u << 20));   //  2 MB (1024,1024)
    float*  b_cat  = (float*) (ws + (size_t)(72u << 20));   //  4 KB

    const dim3 blk(256);
    const int M = 8192;

    cast_bf16<<<dim3(8192), blk, 0, stream>>>(x,   x_bf,   8192 * 1024);
    cast_bf16<<<dim3(1024), blk, 0, stream>>>(wq,  wq_bf,  1024 * 1024);
    cast_bf16<<<dim3(512),  blk, 0, stream>>>(wuk, wuk_bf, 512 * 1024);
    // wcat rows 512..1023 = w_ckv^T
    transpose_cast<<<dim3(16, 32), blk, 0, stream>>>(w_ckv, wcat_t + (size_t)512 * 1024, 1024, 512);
    transpose_cast<<<dim3(32, 16), blk, 0, stream>>>(wuv,   wuv_t,  512,  1024);
    transpose_cast<<<dim3(32, 32), blk, 0, stream>>>(wo,    wo_t,   1024, 1024);
    bias_fold<<<dim3(4), blk, 0, stream>>>(bq, wuk, b_cat);

    // wcat rows 0..511 = wqk[l][d] = sum_n wuk[l][n]*wq[d][n]
    gemm_bt<false, false><<<dim3(8, 4), blk, 0, stream>>>(wuk_bf, wq_bf, nullptr, wcat_t,
                                                          512, 1024, 1024, 1024, 1024, 1024);

    // qc = x @ wcat^T + b_cat     (8192, 1024, K=1024): [q_latent | combined]
    gemm_bt<false, true ><<<dim3(8, 64), blk, 0, stream>>>(x_bf, wcat_t, b_cat, qc,
                                                           M, 1024, 1024, 1024, 1024, 1024);

    // vT = wuv^T @ combined^T     (1024, 8192, K=512)
    gemm_bt<false, false><<<dim3(64, 8), blk, 0, stream>>>(wuv_t, qc + 512, nullptr, vT,
                                                           1024, M, 512, 512, 1024, 8192);

    attn_mfma<<<dim3(16, 16, 8), blk, 0, stream>>>(qc, vT, mask, z);

    // out = z @ wo^T + bo         (8192, 1024, K=1024)
    gemm_bt<true,  true ><<<dim3(8, 64), blk, 0, stream>>>(z, wo_t, bo, out,
                                                           M, 1024, 1024, 1024, 1024, 1024);
}